// Round 9
// baseline (171.129 us; speedup 1.0000x reference)
//
#include <hip/hip_runtime.h>
#include <hip/hip_bf16.h>
#include <math.h>

// Problem constants (B=8, C=128, H=W=64, G=2, gc=64, nH=4, dh=32, Hk=Wk=16, n=256)
#define HW 4096
#define NCH 128

typedef __attribute__((ext_vector_type(8))) short short8;
typedef __attribute__((ext_vector_type(4))) float f32x4;
typedef __attribute__((ext_vector_type(4))) unsigned u32x4;

__device__ __forceinline__ short f2bf(float f) {
  union { __hip_bfloat16 h; short s; } u;
  u.h = __float2bfloat16(f);
  return u.s;
}
__device__ __forceinline__ float bf2f(short s) {
  union { unsigned u; float f; } u;
  u.u = ((unsigned)(unsigned short)s) << 16;
  return u.f;
}

// ---------------------------------------------------------------------------
// K1: fused transpose + q-conv + side prep.
//  y < 8          : transpose + q MFMA
//  y >= 8 (id<64) : wk/wv/wo -> bf16        [overlaps the memory-bound main]
//  y >= 8 (id>=64): delta-packed f16 RPE table (128x128 uint per head):
//     tab[h][row][col] = pack(v[row-1], v[row]-v[row-1]) * log2(e)
// ---------------------------------------------------------------------------
__global__ __launch_bounds__(256) void xq_kernel(
    const float* __restrict__ x, const float* __restrict__ wq,
    const float* __restrict__ wk, const float* __restrict__ wv,
    const float* __restrict__ wo, const float* __restrict__ rpe,
    short* __restrict__ xT, float* __restrict__ qT,
    short* __restrict__ wk_bf, short* __restrict__ wv_bf,
    short* __restrict__ wo_bf, unsigned* __restrict__ tab) {
  __shared__ float s[128][65];  // 33.3 KB
  int tid = threadIdx.x;
  if (blockIdx.y >= 8) {
    int id = (blockIdx.y - 8) * 64 + blockIdx.x;  // 0..319
    if (id < 64) {
      int i = id * 256 + tid;
      wk_bf[i] = f2bf(wk[i]);
      wv_bf[i] = f2bf(wv[i]);
      wo_bf[i] = f2bf(wo[i]);
    } else {
      int i = (id - 64) * 256 + tid;  // 0..65535
      int h = i >> 14, r = i & 16383;
      int row = r >> 7, col = r & 127;
      float lo = 0.f, hi = 0.f;
      if (col < 127) {
        if (row >= 1) lo = rpe[h * 16129 + (row - 1) * 127 + col];
        if (row < 127) hi = rpe[h * 16129 + row * 127 + col];
      }
      union { unsigned u; _Float16 h2[2]; } pk;
      pk.h2[0] = (_Float16)(lo * 1.4426950408889634f);
      pk.h2[1] = (_Float16)((hi - lo) * 1.4426950408889634f);
      tab[i] = pk.u;
    }
    return;
  }
  int b = blockIdx.y;
  int m0 = blockIdx.x * 64;
  {
    int ml = tid & 63, ch = tid >> 6;
#pragma unroll
    for (int i = 0; i < 32; ++i) {
      int c = i * 4 + ch;
      s[c][ml] = x[((size_t)(b * NCH + c)) * HW + m0 + ml];
    }
  }
  __syncthreads();
  // bf16 transpose write, coalesced along c
  {
    int c = tid & 127, mh = tid >> 7;
#pragma unroll
    for (int i = 0; i < 32; ++i) {
      int m = i * 2 + mh;
      xT[((size_t)(b * HW + m0 + m)) * NCH + c] = f2bf(s[c][m]);
    }
  }
  // q MFMA (weights converted inline)
  int w = tid >> 6, lane = tid & 63, l15 = lane & 15, qd = lane >> 4;
  int mrow = w * 16 + l15;
  f32x4 acc[8];
#pragma unroll
  for (int ot = 0; ot < 8; ++ot) acc[ot] = (f32x4){0.f, 0.f, 0.f, 0.f};
#pragma unroll
  for (int kc = 0; kc < 4; ++kc) {
    short8 ah, al;
#pragma unroll
    for (int j = 0; j < 8; ++j) {
      float v = s[kc * 32 + qd * 8 + j][mrow];
      short hi = f2bf(v);
      ah[j] = hi;
      al[j] = f2bf(v - bf2f(hi));
    }
#pragma unroll
    for (int ot = 0; ot < 8; ++ot) {
      const float* wr = wq + (size_t)(ot * 16 + l15) * NCH + kc * 32 + qd * 8;
      f32x4 w0 = *(const f32x4*)wr;
      f32x4 w1 = *(const f32x4*)(wr + 4);
      short8 bh, bl;
#pragma unroll
      for (int j = 0; j < 4; ++j) {
        short h0 = f2bf(w0[j]);
        bh[j] = h0;
        bl[j] = f2bf(w0[j] - bf2f(h0));
        short h1 = f2bf(w1[j]);
        bh[4 + j] = h1;
        bl[4 + j] = f2bf(w1[j] - bf2f(h1));
      }
      acc[ot] = __builtin_amdgcn_mfma_f32_16x16x32_bf16(ah, bh, acc[ot], 0, 0, 0);
      acc[ot] = __builtin_amdgcn_mfma_f32_16x16x32_bf16(al, bh, acc[ot], 0, 0, 0);
      acc[ot] = __builtin_amdgcn_mfma_f32_16x16x32_bf16(ah, bl, acc[ot], 0, 0, 0);
    }
  }
#pragma unroll
  for (int ot = 0; ot < 8; ++ot)
#pragma unroll
    for (int r = 0; r < 4; ++r)
      qT[((size_t)(b * HW + m0 + w * 16 + qd * 4 + r)) * NCH + ot * 16 + l15] =
          acc[ot][r];
}

// ---------------------------------------------------------------------------
// K2: fused conv_offset + grid_sample (proven R7 structure).
// ---------------------------------------------------------------------------
__device__ __forceinline__ float wsum64(float v) {
#pragma unroll
  for (int o = 32; o > 0; o >>= 1) v += __shfl_xor(v, o);
  return v;
}

__global__ __launch_bounds__(256) void conv_sample_kernel(
    const float* __restrict__ qT, const float* __restrict__ w_dw,
    const float* __restrict__ ln_w, const float* __restrict__ w_off,
    const short* __restrict__ xT, float* __restrict__ pos,
    float* __restrict__ dm, short* __restrict__ xsT) {
  int tid = threadIdx.x;
  int c = tid & 63;
  int p = blockIdx.x * 4 + (tid >> 6);
  int bg = blockIdx.y;
  int py = p >> 4, px = p & 15;
  const float* qp = qT + (size_t)(bg >> 1) * HW * NCH + (bg & 1) * 64 + c;
  const float* wd = w_dw + c * 25;
  float acc = 0.f;
#pragma unroll
  for (int ky = 0; ky < 5; ++ky) {
    int iy = 4 * py + ky - 2;
    if (iy < 0 || iy >= 64) continue;
#pragma unroll
    for (int kx = 0; kx < 5; ++kx) {
      int ix = 4 * px + kx - 2;
      if (ix < 0 || ix >= 64) continue;
      acc += wd[ky * 5 + kx] * qp[(size_t)(iy * 64 + ix) * NCH];
    }
  }
  float mean = wsum64(acc) * (1.f / 64.f);
  float msq = wsum64(acc * acc) * (1.f / 64.f);
  float var = msq - mean * mean;  // jnp.var (ddof=0)
  float g = acc * rsqrtf(var + 1e-5f) * ln_w[c];
  g = 0.5f * g * (1.f + erff(g * 0.70710678118654752f));  // exact GELU
  float o0 = wsum64(w_off[c] * g);
  float o1 = wsum64(w_off[64 + c] * g);
  float o2 = wsum64(w_off[128 + c] * g);
  int idx = bg * 256 + p;
  float posy = tanhf(o0) * (1.f / 16.f) + ((py + 0.5f) * (1.f / 8.f) - 1.f);
  float posx = tanhf(o1) * (1.f / 16.f) + ((px + 0.5f) * (1.f / 8.f) - 1.f);
  float dmv = 1.f / (1.f + expf(-o2));
  if (c == 0) {
    pos[idx * 2] = posy;
    pos[idx * 2 + 1] = posx;
    dm[idx] = dmv;
  }
  // sample phase (pos in registers)
  int b = bg >> 1, ch0 = (bg & 1) * 64;
  float gx = (posx + 1.f) * 31.5f;
  float gy = (posy + 1.f) * 31.5f;
  float x0f = floorf(gx), y0f = floorf(gy);
  int ix = (int)x0f, iy = (int)y0f;
  float fx = gx - x0f, fy = gy - y0f;
  float w00 = (1.f - fx) * (1.f - fy), w10 = fx * (1.f - fy);
  float w01 = (1.f - fx) * fy, w11 = fx * fy;
  bool vx0 = (ix >= 0 && ix < 64), vx1 = (ix + 1 >= 0 && ix + 1 < 64);
  bool vy0 = (iy >= 0 && iy < 64), vy1 = (iy + 1 >= 0 && iy + 1 < 64);
  if (!(vx0 && vy0)) w00 = 0.f;
  if (!(vx1 && vy0)) w10 = 0.f;
  if (!(vx0 && vy1)) w01 = 0.f;
  if (!(vx1 && vy1)) w11 = 0.f;
  int x0c = min(max(ix, 0), 63), x1c = min(max(ix + 1, 0), 63);
  int y0c = min(max(iy, 0), 63), y1c = min(max(iy + 1, 0), 63);
  size_t rb = (size_t)b * HW * NCH + ch0 + c;
  float v = w00 * bf2f(xT[rb + (size_t)(y0c * 64 + x0c) * NCH]) +
            w10 * bf2f(xT[rb + (size_t)(y0c * 64 + x1c) * NCH]) +
            w01 * bf2f(xT[rb + (size_t)(y1c * 64 + x0c) * NCH]) +
            w11 * bf2f(xT[rb + (size_t)(y1c * 64 + x1c) * NCH]);
  xsT[((size_t)(b * 256 + p)) * NCH + ch0 + c] = f2bf(v * dmv);
}

// ---------------------------------------------------------------------------
// K3: k AND v in one pass (R8, bit-exact vs split).
// ---------------------------------------------------------------------------
__global__ __launch_bounds__(256) void kv_mfma_kernel(
    const short* __restrict__ xsT, const short* __restrict__ wk_bf,
    const short* __restrict__ wv_bf, short* __restrict__ kbf,
    short* __restrict__ vbf) {
  int tid = threadIdx.x;
  int w = tid >> 6, lane = tid & 63, l15 = lane & 15, qd = lane >> 4;
  int bh = blockIdx.x, b = bh >> 2;
  int n0 = blockIdx.y * 64 + w * 16;
  f32x4 ak[2], av[2];
  ak[0] = (f32x4){0.f, 0.f, 0.f, 0.f};
  ak[1] = (f32x4){0.f, 0.f, 0.f, 0.f};
  av[0] = (f32x4){0.f, 0.f, 0.f, 0.f};
  av[1] = (f32x4){0.f, 0.f, 0.f, 0.f};

  size_t xrow = ((size_t)(b * 256 + n0 + l15)) * NCH + qd * 8;
  short8 xf[4];
#pragma unroll
  for (int kc = 0; kc < 4; ++kc)
    xf[kc] = *(const short8*)&xsT[xrow + kc * 32];
#pragma unroll
  for (int kc = 0; kc < 4; ++kc) {
#pragma unroll
    for (int ot = 0; ot < 2; ++ot) {
      size_t wrow = (size_t)((bh & 3) * 32 + ot * 16 + l15) * NCH + kc * 32 + qd * 8;
      short8 bk = *(const short8*)&wk_bf[wrow];
      short8 bv = *(const short8*)&wv_bf[wrow];
      ak[ot] = __builtin_amdgcn_mfma_f32_16x16x32_bf16(xf[kc], bk, ak[ot], 0, 0, 0);
      av[ot] = __builtin_amdgcn_mfma_f32_16x16x32_bf16(bv, xf[kc], av[ot], 0, 0, 0);
    }
  }
#pragma unroll
  for (int ot = 0; ot < 2; ++ot)
#pragma unroll
    for (int r = 0; r < 4; ++r) {
      kbf[((size_t)(bh * 256 + n0 + qd * 4 + r)) * 32 + ot * 16 + l15] =
          f2bf(ak[ot][r]);
      vbf[((size_t)(bh * 32 + ot * 16 + qd * 4 + r)) * 256 + n0 + l15] =
          f2bf(av[ot][r]);
    }
}

// ---------------------------------------------------------------------------
// K4: MFMA attention — NO LDS table staging (lesson #7: table is 256 KB,
// fully L2-resident; staging it per-block was 9 global_load_lds + a full
// vmcnt drain + an extra barrier + a second acc pass).  Bias words are read
// straight from L2 in the bias loop; P gets a dedicated LDS region, so P is
// written INLINE in the bias loop (no drain pass) and the kernel has ONE
// barrier (meta visibility).  LDS = P 33792 + meta 2048 = 35840 B ->
// 4 blocks/CU unchanged.  Bit-identical arithmetic to R8 (same table words,
// same f16 lerp/exp2/rounding) -> absmax must stay 1.831e-4 exactly.
// ---------------------------------------------------------------------------
#define PROW 264    // bf16 elems per P row (528 B); P = 4*16*264*2 = 33792 B

__global__ __launch_bounds__(256, 4) void attn_kernel(
    const float* __restrict__ qT, const short* __restrict__ kbf,
    const short* __restrict__ vbf, const float* __restrict__ pos,
    const unsigned* __restrict__ tabg, short* __restrict__ outT) {
  __shared__ __align__(16) short s_p[4 * 16 * PROW];   // 33792 B
  __shared__ __align__(16) float s_pxs[256];           // px*31.5
  __shared__ __align__(16) unsigned s_fyrow[256];      // (abs rowoff<<16)|fy16

  int tid = threadIdx.x;
  int wv = tid >> 6;
  int lane = tid & 63;
  int l15 = lane & 15;
  int qd = lane >> 4;
  int bh = blockIdx.y;
  int b = bh >> 2, h = bh & 3;
  int bg = b * 2 + (h >> 1);
  int m0 = blockIdx.x * 64 + wv * 16;

  // block-uniform query row -> gy0
  float ry = ((float)blockIdx.x + 0.5f) * (1.f / 32.f) - 1.f;
  float gy0 = 63.f + ry * 31.5f;                  // in [32, 94]

  // pos + q loads
  float2 p2 = ((const float2*)(pos + (size_t)bg * 512))[tid];
  const float* qg = qT + ((size_t)(b * HW + m0 + l15)) * NCH + h * 32 + qd * 8;
  f32x4 qa0 = *(const f32x4*)qg;
  f32x4 qa1 = *(const f32x4*)(qg + 4);

  // per-n meta (packed, ABSOLUTE row offset): pxs f32; (rowoff<<16)|fy16
  {
    float gy = gy0 + 1.f - p2.x * 31.5f;  // +1 = vertical-pair row offset
    float y0f = floorf(gy);
    union { unsigned short us; _Float16 hh; } fyp;
    fyp.hh = (_Float16)(gy - y0f);
    unsigned rowoff = ((unsigned)(int)y0f) << 7;  // word offset, <= 16256
    s_pxs[tid] = p2.y * 31.5f;
    s_fyrow[tid] = (rowoff << 16) | (unsigned)fyp.us;
  }

  short8 qfrag;
#pragma unroll
  for (int j = 0; j < 4; ++j) {
    qfrag[j] = f2bf(qa0[j]);
    qfrag[4 + j] = f2bf(qa1[j]);
  }

  f32x4 acc[16];
  {
    const short* kb = kbf + ((size_t)bh * 256 + l15) * 32 + qd * 8;
#pragma unroll
    for (int t = 0; t < 16; ++t) {
      short8 kf = *(const short8*)(kb + t * 16 * 32);
      acc[t] = __builtin_amdgcn_mfma_f32_16x16x32_bf16(
          kf, qfrag, (f32x4){0.f, 0.f, 0.f, 0.f}, 0, 0, 0);
    }
  }
  __syncthreads();  // single barrier: meta visible

  int m = m0 + l15;
  float gx0 = ((((float)(m & 63) + 0.5f) * (1.f / 32.f) - 1.f) * 0.5f + 1.f) * 63.f;
  const unsigned* tabrow = tabg + (size_t)h * 16384;
  short* pw = s_p + wv * 16 * PROW + l15 * PROW;
  const short* vb = vbf + ((size_t)bh * 32 + l15) * 256 + qd * 8;
  short8 v0p[4], v1p[4];

  // fused bias + exp2 + inline P write (no drain pass, no second barrier)
  float sm = 0.f;
#pragma unroll
  for (int t = 0; t < 16; ++t) {
    if (t == 12) {  // V prefetch ring under the last 4 bias tiles (acc mostly dead)
#pragma unroll
      for (int j = 0; j < 4; ++j) {
        v0p[j] = *(const short8*)(vb + j * 32);
        v1p[j] = *(const short8*)(vb + 16 * 256 + j * 32);
      }
    }
    int nb = t * 16 + qd * 4;
    f32x4 pxs4 = *(const f32x4*)&s_pxs[nb];   // quad-uniform LDS broadcasts
    u32x4 fr4 = *(const u32x4*)&s_fyrow[nb];
    float e4[4];
#pragma unroll
    for (int r = 0; r < 4; ++r) {
      float gx = gx0 - pxs4[r];
      float x0f = floorf(gx);
      float fx = gx - x0f;
      int xl = (int)x0f;                 // in [0,125] (proven from pos range)
      unsigned fr = fr4[r];
      int ai = (int)(fr >> 16) + xl;
      unsigned left = tabrow[ai];        // L2-resident (256 KB table)
      unsigned right = tabrow[ai + 1];
      union { unsigned u; _Float16 h2[2]; } L, R;
      union { unsigned short us; _Float16 hh; } F;
      L.u = left;                        // (v0, dv) at x
      R.u = right;                       // (v0, dv) at x+1
      F.us = (unsigned short)(fr & 0xffffu);
      _Float16 fy16 = F.hh;
      _Float16 fx16 = (_Float16)fx;
      _Float16 bL = L.h2[0] + fy16 * L.h2[1];   // v_fma_f16
      _Float16 bR = R.h2[0] + fy16 * R.h2[1];   // v_fma_f16
      _Float16 b16 = bL + fx16 * (bR - bL);     // f16 hlerp
      float bias = (float)b16;                  // already * log2(e)
      // scale' = 0.17677669529663688 * log2(e)
      float e = exp2f(fmaf(acc[t][r], 0.25503486121880191f, bias));
      e4[r] = e;
      sm += e;
    }
    short4 pk;
    pk.x = f2bf(e4[0]);
    pk.y = f2bf(e4[1]);
    pk.z = f2bf(e4[2]);
    pk.w = f2bf(e4[3]);
    *(short4*)(pw + t * 16 + qd * 4) = pk;
  }
  sm += __shfl_xor(sm, 16);
  sm += __shfl_xor(sm, 32);
  float inv = 1.f / sm;
  // no barrier: each wave reads only its own P region (same-wave LDS RAW
  // is ordered by the compiler's lgkmcnt waits)

  f32x4 o0 = {0.f, 0.f, 0.f, 0.f}, o1 = {0.f, 0.f, 0.f, 0.f};
  {
    const short* prd = s_p + wv * 16 * PROW + l15 * PROW + qd * 8;
#pragma unroll
    for (int ch = 0; ch < 8; ++ch) {
      short8 pf = *(const short8*)(prd + ch * 32);
      short8 v0c = v0p[ch & 3];
      short8 v1c = v1p[ch & 3];
      if (ch + 4 < 8) {  // refill ring slot (static index after unroll)
        v0p[ch & 3] = *(const short8*)(vb + (ch + 4) * 32);
        v1p[ch & 3] = *(const short8*)(vb + 16 * 256 + (ch + 4) * 32);
      }
      o0 = __builtin_amdgcn_mfma_f32_16x16x32_bf16(v0c, pf, o0, 0, 0, 0);
      o1 = __builtin_amdgcn_mfma_f32_16x16x32_bf16(v1c, pf, o1, 0, 0, 0);
    }
  }
  {
    size_t row = (size_t)(b * HW + m0 + l15) * NCH + h * 32 + qd * 4;
    short4 s0, s1;
    s0.x = f2bf(o0[0] * inv); s0.y = f2bf(o0[1] * inv);
    s0.z = f2bf(o0[2] * inv); s0.w = f2bf(o0[3] * inv);
    s1.x = f2bf(o1[0] * inv); s1.y = f2bf(o1[1] * inv);
    s1.z = f2bf(o1[2] * inv); s1.w = f2bf(o1[3] * inv);
    *(short4*)&outT[row] = s0;
    *(short4*)&outT[row + 16] = s1;
  }
}

// ---------------------------------------------------------------------------
// K5: final conv via MFMA: out[b][o][m] = sum_c wo[o][c] * outT[b][m][c]
// ---------------------------------------------------------------------------
__global__ __launch_bounds__(256) void wo_mfma_kernel(
    const short* __restrict__ attnT, const short* __restrict__ wo_bf,
    float* __restrict__ out) {
  int tid = threadIdx.x;
  int wv = tid >> 6;
  int lane = tid & 63;
  int l15 = lane & 15;
  int qd = lane >> 4;
  int b = blockIdx.x >> 6;
  int m0 = (blockIdx.x & 63) * 64 + wv * 16;

  f32x4 acc[8];
#pragma unroll
  for (int ot = 0; ot < 8; ++ot) acc[ot] = (f32x4){0.f, 0.f, 0.f, 0.f};

  const short* arow = attnT + (size_t)(b * HW + m0 + l15) * NCH + qd * 8;
  const short* wrow = wo_bf + (size_t)l15 * NCH + qd * 8;
#pragma unroll
  for (int kc = 0; kc < 4; ++kc) {
    short8 afrag = *(const short8*)(arow + kc * 32);
#pragma unroll
    for (int ot = 0; ot < 8; ++ot) {
      short8 bfrag = *(const short8*)(wrow + (size_t)ot * 16 * NCH + kc * 32);
      acc[ot] = __builtin_amdgcn_mfma_f32_16x16x32_bf16(afrag, bfrag, acc[ot],
                                                        0, 0, 0);
    }
  }
#pragma unroll
  for (int ot = 0; ot < 8; ++ot) {
    float* op = out + ((size_t)b * NCH + ot * 16 + l15) * HW + m0 + qd * 4;
    *(f32x4*)op = acc[ot];
  }
}

// ---------------------------------------------------------------------------
// launch  (5 kernels: xq(+prep), conv+sample, kv(merged), attn, wo)
// ---------------------------------------------------------------------------
extern "C" void kernel_launch(void* const* d_in, const int* in_sizes, int n_in,
                              void* d_out, int out_size, void* d_ws,
                              size_t ws_size, hipStream_t stream) {
  const float* x = (const float*)d_in[0];
  const float* w_dw = (const float*)d_in[1];
  const float* ln_w = (const float*)d_in[2];
  const float* w_off = (const float*)d_in[3];
  const float* wq = (const float*)d_in[4];
  const float* wk = (const float*)d_in[5];
  const float* wv = (const float*)d_in[6];
  const float* wo = (const float*)d_in[7];
  const float* rpe = (const float*)d_in[8];
  float* out = (float*)d_out;

  // qT lives in d_out (dead before wo_mfma writes out).
  // outT aliases xT (xT dead after conv_sample, before attn writes outT).
  float* qT = out;
  short* sb = (short*)d_ws;
  short* xT = sb;                       // 4194304 bf16 (8.4 MB) [alias: outT]
  short* outT = sb;
  short* xsT = sb + 4194304;            // 262144
  short* kbf = sb + 4456448;            // 262144
  short* vbf = sb + 4718592;            // 262144
  short* wk_bf = sb + 4980736;          // 16384
  short* wv_bf = sb + 4997120;          // 16384
  short* wo_bf = sb + 5013504;          // 16384
  unsigned* tab = (unsigned*)(sb + 5029888);  // 65536 uints (256 KB, 16B-al)
  float* pos = (float*)(sb + 5160960);  // 8192 fp32
  float* dm = pos + 8192;               // 4096 fp32
  // total ~10.4 MB

  xq_kernel<<<dim3(64, 13), 256, 0, stream>>>(x, wq, wk, wv, wo, rpe, xT, qT,
                                              wk_bf, wv_bf, wo_bf, tab);
  conv_sample_kernel<<<dim3(64, 16), 256, 0, stream>>>(qT, w_dw, ln_w, w_off,
                                                       xT, pos, dm, xsT);
  kv_mfma_kernel<<<dim3(32, 4), 256, 0, stream>>>(xsT, wk_bf, wv_bf, kbf,
                                                  vbf);
  attn_kernel<<<dim3(64, 32), 256, 0, stream>>>(qT, kbf, vbf, pos, tab, outT);
  wo_mfma_kernel<<<512, 256, 0, stream>>>(outT, wo_bf, out);
}

// Round 10
// 162.533 us; speedup vs baseline: 1.0529x; 1.0529x over previous
//
#include <hip/hip_runtime.h>
#include <hip/hip_bf16.h>
#include <math.h>

// Problem constants (B=8, C=128, H=W=64, G=2, gc=64, nH=4, dh=32, Hk=Wk=16, n=256)
#define HW 4096
#define NCH 128

typedef __attribute__((ext_vector_type(8))) short short8;
typedef __attribute__((ext_vector_type(4))) float f32x4;
typedef __attribute__((ext_vector_type(4))) unsigned u32x4;

__device__ __forceinline__ short f2bf(float f) {
  union { __hip_bfloat16 h; short s; } u;
  u.h = __float2bfloat16(f);
  return u.s;
}
__device__ __forceinline__ float bf2f(short s) {
  union { unsigned u; float f; } u;
  u.u = ((unsigned)(unsigned short)s) << 16;
  return u.f;
}

// ---------------------------------------------------------------------------
// K1: fused transpose + q-conv + side prep.
//  y < 8          : transpose + q MFMA
//  y >= 8 (id<64) : wk/wv/wo -> bf16        [overlaps the memory-bound main]
//  y >= 8 (id>=64): delta-packed f16 RPE table (128x128 uint per head):
//     tab[h][row][col] = pack(v[row-1], v[row]-v[row-1]) * log2(e)
// ---------------------------------------------------------------------------
__global__ __launch_bounds__(256) void xq_kernel(
    const float* __restrict__ x, const float* __restrict__ wq,
    const float* __restrict__ wk, const float* __restrict__ wv,
    const float* __restrict__ wo, const float* __restrict__ rpe,
    short* __restrict__ xT, float* __restrict__ qT,
    short* __restrict__ wk_bf, short* __restrict__ wv_bf,
    short* __restrict__ wo_bf, unsigned* __restrict__ tab) {
  __shared__ float s[128][65];  // 33.3 KB
  int tid = threadIdx.x;
  if (blockIdx.y >= 8) {
    int id = (blockIdx.y - 8) * 64 + blockIdx.x;  // 0..319
    if (id < 64) {
      int i = id * 256 + tid;
      wk_bf[i] = f2bf(wk[i]);
      wv_bf[i] = f2bf(wv[i]);
      wo_bf[i] = f2bf(wo[i]);
    } else {
      int i = (id - 64) * 256 + tid;  // 0..65535
      int h = i >> 14, r = i & 16383;
      int row = r >> 7, col = r & 127;
      float lo = 0.f, hi = 0.f;
      if (col < 127) {
        if (row >= 1) lo = rpe[h * 16129 + (row - 1) * 127 + col];
        if (row < 127) hi = rpe[h * 16129 + row * 127 + col];
      }
      union { unsigned u; _Float16 h2[2]; } pk;
      pk.h2[0] = (_Float16)(lo * 1.4426950408889634f);
      pk.h2[1] = (_Float16)((hi - lo) * 1.4426950408889634f);
      tab[i] = pk.u;
    }
    return;
  }
  int b = blockIdx.y;
  int m0 = blockIdx.x * 64;
  {
    int ml = tid & 63, ch = tid >> 6;
#pragma unroll
    for (int i = 0; i < 32; ++i) {
      int c = i * 4 + ch;
      s[c][ml] = x[((size_t)(b * NCH + c)) * HW + m0 + ml];
    }
  }
  __syncthreads();
  // bf16 transpose write, coalesced along c
  {
    int c = tid & 127, mh = tid >> 7;
#pragma unroll
    for (int i = 0; i < 32; ++i) {
      int m = i * 2 + mh;
      xT[((size_t)(b * HW + m0 + m)) * NCH + c] = f2bf(s[c][m]);
    }
  }
  // q MFMA (weights converted inline)
  int w = tid >> 6, lane = tid & 63, l15 = lane & 15, qd = lane >> 4;
  int mrow = w * 16 + l15;
  f32x4 acc[8];
#pragma unroll
  for (int ot = 0; ot < 8; ++ot) acc[ot] = (f32x4){0.f, 0.f, 0.f, 0.f};
#pragma unroll
  for (int kc = 0; kc < 4; ++kc) {
    short8 ah, al;
#pragma unroll
    for (int j = 0; j < 8; ++j) {
      float v = s[kc * 32 + qd * 8 + j][mrow];
      short hi = f2bf(v);
      ah[j] = hi;
      al[j] = f2bf(v - bf2f(hi));
    }
#pragma unroll
    for (int ot = 0; ot < 8; ++ot) {
      const float* wr = wq + (size_t)(ot * 16 + l15) * NCH + kc * 32 + qd * 8;
      f32x4 w0 = *(const f32x4*)wr;
      f32x4 w1 = *(const f32x4*)(wr + 4);
      short8 bh, bl;
#pragma unroll
      for (int j = 0; j < 4; ++j) {
        short h0 = f2bf(w0[j]);
        bh[j] = h0;
        bl[j] = f2bf(w0[j] - bf2f(h0));
        short h1 = f2bf(w1[j]);
        bh[4 + j] = h1;
        bl[4 + j] = f2bf(w1[j] - bf2f(h1));
      }
      acc[ot] = __builtin_amdgcn_mfma_f32_16x16x32_bf16(ah, bh, acc[ot], 0, 0, 0);
      acc[ot] = __builtin_amdgcn_mfma_f32_16x16x32_bf16(al, bh, acc[ot], 0, 0, 0);
      acc[ot] = __builtin_amdgcn_mfma_f32_16x16x32_bf16(ah, bl, acc[ot], 0, 0, 0);
    }
  }
#pragma unroll
  for (int ot = 0; ot < 8; ++ot)
#pragma unroll
    for (int r = 0; r < 4; ++r)
      qT[((size_t)(b * HW + m0 + w * 16 + qd * 4 + r)) * NCH + ot * 16 + l15] =
          acc[ot][r];
}

// ---------------------------------------------------------------------------
// K2: fused conv_offset + grid_sample (proven R7 structure).
// ---------------------------------------------------------------------------
__device__ __forceinline__ float wsum64(float v) {
#pragma unroll
  for (int o = 32; o > 0; o >>= 1) v += __shfl_xor(v, o);
  return v;
}

__global__ __launch_bounds__(256) void conv_sample_kernel(
    const float* __restrict__ qT, const float* __restrict__ w_dw,
    const float* __restrict__ ln_w, const float* __restrict__ w_off,
    const short* __restrict__ xT, float* __restrict__ pos,
    float* __restrict__ dm, short* __restrict__ xsT) {
  int tid = threadIdx.x;
  int c = tid & 63;
  int p = blockIdx.x * 4 + (tid >> 6);
  int bg = blockIdx.y;
  int py = p >> 4, px = p & 15;
  const float* qp = qT + (size_t)(bg >> 1) * HW * NCH + (bg & 1) * 64 + c;
  const float* wd = w_dw + c * 25;
  float acc = 0.f;
#pragma unroll
  for (int ky = 0; ky < 5; ++ky) {
    int iy = 4 * py + ky - 2;
    if (iy < 0 || iy >= 64) continue;
#pragma unroll
    for (int kx = 0; kx < 5; ++kx) {
      int ix = 4 * px + kx - 2;
      if (ix < 0 || ix >= 64) continue;
      acc += wd[ky * 5 + kx] * qp[(size_t)(iy * 64 + ix) * NCH];
    }
  }
  float mean = wsum64(acc) * (1.f / 64.f);
  float msq = wsum64(acc * acc) * (1.f / 64.f);
  float var = msq - mean * mean;  // jnp.var (ddof=0)
  float g = acc * rsqrtf(var + 1e-5f) * ln_w[c];
  g = 0.5f * g * (1.f + erff(g * 0.70710678118654752f));  // exact GELU
  float o0 = wsum64(w_off[c] * g);
  float o1 = wsum64(w_off[64 + c] * g);
  float o2 = wsum64(w_off[128 + c] * g);
  int idx = bg * 256 + p;
  float posy = tanhf(o0) * (1.f / 16.f) + ((py + 0.5f) * (1.f / 8.f) - 1.f);
  float posx = tanhf(o1) * (1.f / 16.f) + ((px + 0.5f) * (1.f / 8.f) - 1.f);
  float dmv = 1.f / (1.f + expf(-o2));
  if (c == 0) {
    pos[idx * 2] = posy;
    pos[idx * 2 + 1] = posx;
    dm[idx] = dmv;
  }
  // sample phase (pos in registers)
  int b = bg >> 1, ch0 = (bg & 1) * 64;
  float gx = (posx + 1.f) * 31.5f;
  float gy = (posy + 1.f) * 31.5f;
  float x0f = floorf(gx), y0f = floorf(gy);
  int ix = (int)x0f, iy = (int)y0f;
  float fx = gx - x0f, fy = gy - y0f;
  float w00 = (1.f - fx) * (1.f - fy), w10 = fx * (1.f - fy);
  float w01 = (1.f - fx) * fy, w11 = fx * fy;
  bool vx0 = (ix >= 0 && ix < 64), vx1 = (ix + 1 >= 0 && ix + 1 < 64);
  bool vy0 = (iy >= 0 && iy < 64), vy1 = (iy + 1 >= 0 && iy + 1 < 64);
  if (!(vx0 && vy0)) w00 = 0.f;
  if (!(vx1 && vy0)) w10 = 0.f;
  if (!(vx0 && vy1)) w01 = 0.f;
  if (!(vx1 && vy1)) w11 = 0.f;
  int x0c = min(max(ix, 0), 63), x1c = min(max(ix + 1, 0), 63);
  int y0c = min(max(iy, 0), 63), y1c = min(max(iy + 1, 0), 63);
  size_t rb = (size_t)b * HW * NCH + ch0 + c;
  float v = w00 * bf2f(xT[rb + (size_t)(y0c * 64 + x0c) * NCH]) +
            w10 * bf2f(xT[rb + (size_t)(y0c * 64 + x1c) * NCH]) +
            w01 * bf2f(xT[rb + (size_t)(y1c * 64 + x0c) * NCH]) +
            w11 * bf2f(xT[rb + (size_t)(y1c * 64 + x1c) * NCH]);
  xsT[((size_t)(b * 256 + p)) * NCH + ch0 + c] = f2bf(v * dmv);
}

// ---------------------------------------------------------------------------
// K3: k AND v in one pass (bit-exact vs split).
// ---------------------------------------------------------------------------
__global__ __launch_bounds__(256) void kv_mfma_kernel(
    const short* __restrict__ xsT, const short* __restrict__ wk_bf,
    const short* __restrict__ wv_bf, short* __restrict__ kbf,
    short* __restrict__ vbf) {
  int tid = threadIdx.x;
  int w = tid >> 6, lane = tid & 63, l15 = lane & 15, qd = lane >> 4;
  int bh = blockIdx.x, b = bh >> 2;
  int n0 = blockIdx.y * 64 + w * 16;
  f32x4 ak[2], av[2];
  ak[0] = (f32x4){0.f, 0.f, 0.f, 0.f};
  ak[1] = (f32x4){0.f, 0.f, 0.f, 0.f};
  av[0] = (f32x4){0.f, 0.f, 0.f, 0.f};
  av[1] = (f32x4){0.f, 0.f, 0.f, 0.f};

  size_t xrow = ((size_t)(b * 256 + n0 + l15)) * NCH + qd * 8;
  short8 xf[4];
#pragma unroll
  for (int kc = 0; kc < 4; ++kc)
    xf[kc] = *(const short8*)&xsT[xrow + kc * 32];
#pragma unroll
  for (int kc = 0; kc < 4; ++kc) {
#pragma unroll
    for (int ot = 0; ot < 2; ++ot) {
      size_t wrow = (size_t)((bh & 3) * 32 + ot * 16 + l15) * NCH + kc * 32 + qd * 8;
      short8 bk = *(const short8*)&wk_bf[wrow];
      short8 bv = *(const short8*)&wv_bf[wrow];
      ak[ot] = __builtin_amdgcn_mfma_f32_16x16x32_bf16(xf[kc], bk, ak[ot], 0, 0, 0);
      av[ot] = __builtin_amdgcn_mfma_f32_16x16x32_bf16(bv, xf[kc], av[ot], 0, 0, 0);
    }
  }
#pragma unroll
  for (int ot = 0; ot < 2; ++ot)
#pragma unroll
    for (int r = 0; r < 4; ++r) {
      kbf[((size_t)(bh * 256 + n0 + qd * 4 + r)) * 32 + ot * 16 + l15] =
          f2bf(ak[ot][r]);
      vbf[((size_t)(bh * 32 + ot * 16 + qd * 4 + r)) * 256 + n0 + l15] =
          f2bf(av[ot][r]);
    }
}

// ---------------------------------------------------------------------------
// K4: MFMA attention (best-known R8 structure, reverted from the R9
// no-staging experiment: L2 random gathers cost +10us vs the staged
// ds_read2 path — LDS staging is the right call for data-dependent
// per-lane gathers, lesson #7 notwithstanding).
// 66-row delta-packed f16 table window (33792 B) + packed per-n meta
// (2 KB) = 35840 B -> 4 blocks/CU.  No-max softmax; exp2 fused into the
// bias loop; 4-deep static-ring V prefetch; P overlays the table.
// ---------------------------------------------------------------------------
#define PROW 264    // bf16 elems per P row (528 B); P = 4*16*264*2 = 33792 B
#define TROWS 66    // staged rows; access index in [1,65] (proof in notes)

struct __attribute__((packed)) upair { unsigned lo, hi; };

__global__ __launch_bounds__(256, 4) void attn_kernel(
    const float* __restrict__ qT, const short* __restrict__ kbf,
    const short* __restrict__ vbf, const float* __restrict__ pos,
    const unsigned* __restrict__ tabg, short* __restrict__ outT) {
  __shared__ __align__(16) unsigned s_tab[TROWS * 128];  // 33792 B
  __shared__ __align__(16) float s_pxs[256];             // px*31.5
  __shared__ __align__(16) unsigned s_fyrow[256];        // (rowoff<<16)|fy16
  short* s_p = (short*)s_tab;

  int tid = threadIdx.x;
  int wv = tid >> 6;
  int lane = tid & 63;
  int l15 = lane & 15;
  int qd = lane >> 4;
  int bh = blockIdx.y;
  int b = bh >> 2, h = bh & 3;
  int bg = b * 2 + (h >> 1);
  int m0 = blockIdx.x * 64 + wv * 16;

  // block-uniform query row -> gy0 and the 66-row staging window
  float ry = ((float)blockIdx.x + 0.5f) * (1.f / 32.f) - 1.f;
  float gy0 = 63.f + ry * 31.5f;                  // in [32, 94]
  int row0 = (int)floorf(gy0) - 32;               // in [0, 61]

  // ---- issue pos + q + first 8 K loads BEFORE staging (oldest in queue) ----
  float2 p2 = ((const float2*)(pos + (size_t)bg * 512))[tid];
  const float* qg = qT + ((size_t)(b * HW + m0 + l15)) * NCH + h * 32 + qd * 8;
  f32x4 qa0 = *(const f32x4*)qg;
  f32x4 qa1 = *(const f32x4*)(qg + 4);
  const short* kb = kbf + ((size_t)bh * 256 + l15) * 32 + qd * 8;
  short8 kf[8];
#pragma unroll
  for (int t = 0; t < 8; ++t) kf[t] = *(const short8*)(kb + t * 16 * 32);

  // ---- async-stage the window (2112 uint4) straight into LDS ----
  {
    const uint4* src = (const uint4*)(tabg + (size_t)h * 16384 + row0 * 128);
    uint4* dst = (uint4*)s_tab;
#pragma unroll
    for (int i = 0; i < 8; ++i)
      __builtin_amdgcn_global_load_lds(
          (const __attribute__((address_space(1))) void*)(src + i * 256 + tid),
          (__attribute__((address_space(3))) void*)(dst + i * 256 + tid), 16,
          0, 0);
    if (tid < 64)
      __builtin_amdgcn_global_load_lds(
          (const __attribute__((address_space(1))) void*)(src + 2048 + tid),
          (__attribute__((address_space(3))) void*)(dst + 2048 + tid), 16,
          0, 0);
  }

  // ---- meta compute + q convert + first 8 QK MFMAs (under staging flight) --
  {
    float gyb = gy0 - (float)row0 + 1.f;  // fold row0 + the +1 row offset
    float gy = gyb - p2.x * 31.5f;        // in [1, 66) within window
    float y0f = floorf(gy);
    union { unsigned short us; _Float16 hh; } fyp;
    fyp.hh = (_Float16)(gy - y0f);
    unsigned rowoff = ((unsigned)(int)y0f) << 7;  // word offset, <= 8320
    s_pxs[tid] = p2.y * 31.5f;
    s_fyrow[tid] = (rowoff << 16) | (unsigned)fyp.us;
  }
  short8 qfrag;
#pragma unroll
  for (int j = 0; j < 4; ++j) {
    qfrag[j] = f2bf(qa0[j]);
    qfrag[4 + j] = f2bf(qa1[j]);
  }

  f32x4 acc[16];
#pragma unroll
  for (int t = 0; t < 8; ++t)
    acc[t] = __builtin_amdgcn_mfma_f32_16x16x32_bf16(
        kf[t], qfrag, (f32x4){0.f, 0.f, 0.f, 0.f}, 0, 0, 0);

  // issue second 8 K loads (they complete with/after the staging drain)
  short8 kf2[8];
#pragma unroll
  for (int t = 0; t < 8; ++t) kf2[t] = *(const short8*)(kb + (t + 8) * 16 * 32);

  __syncthreads();  // b1: staging (vmcnt) + meta (lgkmcnt) done

#pragma unroll
  for (int t = 0; t < 8; ++t)
    acc[8 + t] = __builtin_amdgcn_mfma_f32_16x16x32_bf16(
        kf2[t], qfrag, (f32x4){0.f, 0.f, 0.f, 0.f}, 0, 0, 0);

  int m = m0 + l15;
  float gx0 = ((((float)(m & 63) + 0.5f) * (1.f / 32.f) - 1.f) * 0.5f + 1.f) * 63.f;

  // fused bias + exp2 (no-max softmax): acc <- raw exp, sm accumulated
  float sm = 0.f;
#pragma unroll
  for (int t = 0; t < 16; ++t) {
    int nb = t * 16 + qd * 4;
    f32x4 pxs4 = *(const f32x4*)&s_pxs[nb];   // quad-uniform LDS broadcasts
    u32x4 fr4 = *(const u32x4*)&s_fyrow[nb];
#pragma unroll
    for (int r = 0; r < 4; ++r) {
      float gx = gx0 - pxs4[r];
      float x0f = floorf(gx);
      float fx = gx - x0f;
      int xl = (int)x0f;                 // in [0,125] (proven from pos range)
      unsigned fr = fr4[r];
      int ai = (int)(fr >> 16) + xl;
      upair pr = *(const upair*)(s_tab + ai);  // ds_read2_b32: left+right
      union { unsigned u; _Float16 h2[2]; } L, R;
      union { unsigned short us; _Float16 hh; } F;
      L.u = pr.lo;                       // (v0, dv) at x
      R.u = pr.hi;                       // (v0, dv) at x+1
      F.us = (unsigned short)(fr & 0xffffu);
      _Float16 fy16 = F.hh;
      _Float16 fx16 = (_Float16)fx;
      _Float16 bL = L.h2[0] + fy16 * L.h2[1];   // v_fma_f16
      _Float16 bR = R.h2[0] + fy16 * R.h2[1];   // v_fma_f16
      _Float16 b16 = bL + fx16 * (bR - bL);     // f16 hlerp
      float bias = (float)b16;                  // already * log2(e)
      // scale' = 0.17677669529663688 * log2(e)
      float e = exp2f(fmaf(acc[t][r], 0.25503486121880191f, bias));
      acc[t][r] = e;
      sm += e;
    }
  }
  sm += __shfl_xor(sm, 16);
  sm += __shfl_xor(sm, 32);
  float inv = 1.f / sm;

  __syncthreads();  // all table reads done before P overlays

  // issue 4-deep V prefetch ring BEFORE the P drain (drain covers L2 latency)
  const short* vb = vbf + ((size_t)bh * 32 + l15) * 256 + qd * 8;
  short8 v0p[4], v1p[4];
#pragma unroll
  for (int j = 0; j < 4; ++j) {
    v0p[j] = *(const short8*)(vb + j * 32);
    v1p[j] = *(const short8*)(vb + 16 * 256 + j * 32);
  }

  // P drain: write raw exp (bf16); normalization folded into the epilogue
  {
    short* pw = s_p + wv * 16 * PROW + l15 * PROW;
#pragma unroll
    for (int t = 0; t < 16; ++t) {
      short4 pk;
      pk.x = f2bf(acc[t][0]);
      pk.y = f2bf(acc[t][1]);
      pk.z = f2bf(acc[t][2]);
      pk.w = f2bf(acc[t][3]);
      *(short4*)(pw + t * 16 + qd * 4) = pk;
    }
  }
  // no barrier: each wave reads only its own P region

  f32x4 o0 = {0.f, 0.f, 0.f, 0.f}, o1 = {0.f, 0.f, 0.f, 0.f};
  {
    const short* prd = s_p + wv * 16 * PROW + l15 * PROW + qd * 8;
#pragma unroll
    for (int ch = 0; ch < 8; ++ch) {
      short8 pf = *(const short8*)(prd + ch * 32);
      short8 v0c = v0p[ch & 3];
      short8 v1c = v1p[ch & 3];
      if (ch + 4 < 8) {  // refill ring slot (static index after unroll)
        v0p[ch & 3] = *(const short8*)(vb + (ch + 4) * 32);
        v1p[ch & 3] = *(const short8*)(vb + 16 * 256 + (ch + 4) * 32);
      }
      o0 = __builtin_amdgcn_mfma_f32_16x16x32_bf16(v0c, pf, o0, 0, 0, 0);
      o1 = __builtin_amdgcn_mfma_f32_16x16x32_bf16(v1c, pf, o1, 0, 0, 0);
    }
  }
  {
    size_t row = (size_t)(b * HW + m0 + l15) * NCH + h * 32 + qd * 4;
    short4 s0, s1;
    s0.x = f2bf(o0[0] * inv); s0.y = f2bf(o0[1] * inv);
    s0.z = f2bf(o0[2] * inv); s0.w = f2bf(o0[3] * inv);
    s1.x = f2bf(o1[0] * inv); s1.y = f2bf(o1[1] * inv);
    s1.z = f2bf(o1[2] * inv); s1.w = f2bf(o1[3] * inv);
    *(short4*)&outT[row] = s0;
    *(short4*)&outT[row + 16] = s1;
  }
}

// ---------------------------------------------------------------------------
// K5: final conv via MFMA: out[b][o][m] = sum_c wo[o][c] * outT[b][m][c]
// ---------------------------------------------------------------------------
__global__ __launch_bounds__(256) void wo_mfma_kernel(
    const short* __restrict__ attnT, const short* __restrict__ wo_bf,
    float* __restrict__ out) {
  int tid = threadIdx.x;
  int wv = tid >> 6;
  int lane = tid & 63;
  int l15 = lane & 15;
  int qd = lane >> 4;
  int b = blockIdx.x >> 6;
  int m0 = (blockIdx.x & 63) * 64 + wv * 16;

  f32x4 acc[8];
#pragma unroll
  for (int ot = 0; ot < 8; ++ot) acc[ot] = (f32x4){0.f, 0.f, 0.f, 0.f};

  const short* arow = attnT + (size_t)(b * HW + m0 + l15) * NCH + qd * 8;
  const short* wrow = wo_bf + (size_t)l15 * NCH + qd * 8;
#pragma unroll
  for (int kc = 0; kc < 4; ++kc) {
    short8 afrag = *(const short8*)(arow + kc * 32);
#pragma unroll
    for (int ot = 0; ot < 8; ++ot) {
      short8 bfrag = *(const short8*)(wrow + (size_t)ot * 16 * NCH + kc * 32);
      acc[ot] = __builtin_amdgcn_mfma_f32_16x16x32_bf16(afrag, bfrag, acc[ot],
                                                        0, 0, 0);
    }
  }
#pragma unroll
  for (int ot = 0; ot < 8; ++ot) {
    float* op = out + ((size_t)b * NCH + ot * 16 + l15) * HW + m0 + qd * 4;
    *(f32x4*)op = acc[ot];
  }
}

// ---------------------------------------------------------------------------
// launch  (5 kernels: xq(+prep), conv+sample, kv(merged), attn, wo)
// ---------------------------------------------------------------------------
extern "C" void kernel_launch(void* const* d_in, const int* in_sizes, int n_in,
                              void* d_out, int out_size, void* d_ws,
                              size_t ws_size, hipStream_t stream) {
  const float* x = (const float*)d_in[0];
  const float* w_dw = (const float*)d_in[1];
  const float* ln_w = (const float*)d_in[2];
  const float* w_off = (const float*)d_in[3];
  const float* wq = (const float*)d_in[4];
  const float* wk = (const float*)d_in[5];
  const float* wv = (const float*)d_in[6];
  const float* wo = (const float*)d_in[7];
  const float* rpe = (const float*)d_in[8];
  float* out = (float*)d_out;

  // qT lives in d_out (dead before wo_mfma writes out).
  // outT aliases xT (xT dead after conv_sample, before attn writes outT).
  float* qT = out;
  short* sb = (short*)d_ws;
  short* xT = sb;                       // 4194304 bf16 (8.4 MB) [alias: outT]
  short* outT = sb;
  short* xsT = sb + 4194304;            // 262144
  short* kbf = sb + 4456448;            // 262144
  short* vbf = sb + 4718592;            // 262144
  short* wk_bf = sb + 4980736;          // 16384
  short* wv_bf = sb + 4997120;          // 16384
  short* wo_bf = sb + 5013504;          // 16384
  unsigned* tab = (unsigned*)(sb + 5029888);  // 65536 uints (256 KB, 16B-al)
  float* pos = (float*)(sb + 5160960);  // 8192 fp32
  float* dm = pos + 8192;               // 4096 fp32
  // total ~10.4 MB

  xq_kernel<<<dim3(64, 13), 256, 0, stream>>>(x, wq, wk, wv, wo, rpe, xT, qT,
                                              wk_bf, wv_bf, wo_bf, tab);
  conv_sample_kernel<<<dim3(64, 16), 256, 0, stream>>>(qT, w_dw, ln_w, w_off,
                                                       xT, pos, dm, xsT);
  kv_mfma_kernel<<<dim3(32, 4), 256, 0, stream>>>(xsT, wk_bf, wv_bf, kbf,
                                                  vbf);
  attn_kernel<<<dim3(64, 32), 256, 0, stream>>>(qT, kbf, vbf, pos, tab, outT);
  wo_mfma_kernel<<<512, 256, 0, stream>>>(outT, wo_bf, out);
}